// Round 5
// baseline (2227.376 us; speedup 1.0000x reference)
//
#include <hip/hip_runtime.h>
#include <math.h>

#define NG  16384
#define NN  32
#define DD  128
#define RR  32
#define OO  64
#define HHH 256

// M[o][r] = sum_h Wl[o][h] * V[h][r]   (collapses readout@Wl.T into pooled@M.T)
__global__ void precompute_M_kernel(const float* __restrict__ Wl,
                                    const float* __restrict__ V,
                                    float* __restrict__ M) {
    int t = blockIdx.x * blockDim.x + threadIdx.x;   // 0..2047
    int o = t >> 5;
    int r = t & 31;
    float s = 0.f;
#pragma unroll 8
    for (int hh = 0; hh < HHH; ++hh)
        s = fmaf(Wl[o * HHH + hh], V[hh * RR + r], s);
    M[o * RR + r] = s;
}

__device__ __forceinline__ void fma4(float4& a, float s, const float4& w) {
    a.x = fmaf(s, w.x, a.x);
    a.y = fmaf(s, w.y, a.y);
    a.z = fmaf(s, w.z, a.z);
    a.w = fmaf(s, w.w, a.w);
}

typedef const float __attribute__((address_space(1))) gfloat;
typedef float       __attribute__((address_space(3))) lfloat;

// R5: R3's symmetric 4n x 4r lane tile (minimal per-lane read volume:
// n_pl*128 + 128*r_pl is minimized at 4x4), with:
//  - W via divergent global float4 loads (8 addrs x 8-way bcast / wave-load,
//    L2-hot 16 KB) -> W leaves LDS; no __syncthreads anywhere; each W quad
//    shared in-register across 2 interleaved graphs.
//  - h via global_load_lds into per-wave double-buffered XOR-rotated chunks
//    (slot t of row n holds quad (t+n)&7 -> reads hit 8 distinct bank-quads,
//    DMA rows stay in one 128B segment).
//  - vmcnt(0) waits only cover a DMA issued one full chunk-compute earlier;
//    next pair's first chunks are issued under the current pair's tail.
__global__ __launch_bounds__(128, 2)
void gin_main_kernel(const float* __restrict__ hsrc,
                     const float* __restrict__ W,
                     const float* __restrict__ M,
                     const float* __restrict__ bl,
                     float* __restrict__ out) {
    // [wave][slot][graph-of-pair][32 rows x 32 floats] = 32 KB/block
    __shared__ float sH[2][2][2][1024];

    const int tid  = threadIdx.x;
    const int lane = tid & 63;
    const int wv   = tid >> 6;
    const int rg   = lane & 7;     // r-group: r = rg*4 .. rg*4+3
    const int ng   = lane >> 3;    // n-group: n = ng, ng+8, ng+16, ng+24
    const int r0   = rg * 4;
    const int rowL = lane >> 3;    // DMA: row within 8-row group
    const int t8   = lane & 7;     // DMA: slot within row
    const int sq   = (t8 + rowL) & 7;   // global quad stored in this slot

    const int waveId = blockIdx.x * 2 + wv;     // 0..4095
    const int gbase  = waveId * 4;              // 4 graphs per wave
    const float blv  = bl[lane];

    // stage one 32x32f chunk of both graphs of a pair into slot `slot`
    auto issue_chunk = [&](const float* hg0, const float* hg1, int c, int slot) {
        const int goff = c * 32 + sq * 4;
#pragma unroll
        for (int j = 0; j < 4; ++j) {
            const float* gp = hg0 + (j * 8 + rowL) * DD + goff;
            __builtin_amdgcn_global_load_lds((gfloat*)gp,
                                             (lfloat*)(&sH[wv][slot][0][j * 256]), 16, 0, 0);
        }
#pragma unroll
        for (int j = 0; j < 4; ++j) {
            const float* gp = hg1 + (j * 8 + rowL) * DD + goff;
            __builtin_amdgcn_global_load_lds((gfloat*)gp,
                                             (lfloat*)(&sH[wv][slot][1][j * 256]), 16, 0, 0);
        }
    };

    {
        const float* hg0 = hsrc + (size_t)gbase * (NN * DD);
        issue_chunk(hg0, hg0 + NN * DD, 0, 0);
        issue_chunk(hg0, hg0 + NN * DD, 1, 1);
    }

#pragma unroll 1
    for (int pi = 0; pi < 2; ++pi) {
        const float* hg0 = hsrc + (size_t)(gbase + pi * 2) * (NN * DD);
        const float* hg1 = hg0 + NN * DD;
        const float* hn0 = hg1 + NN * DD;        // next pair (unused when pi==1)
        const float* hn1 = hn0 + NN * DD;

        float4 aA0 = make_float4(0.f, 0.f, 0.f, 0.f);
        float4 aA1 = aA0, aA2 = aA0, aA3 = aA0;  // graph 0: feat[ng+8k][r0..r0+3]
        float4 aB0 = aA0, aB1 = aA0, aB2 = aA0, aB3 = aA0;  // graph 1

#pragma unroll
        for (int c = 0; c < 4; ++c) {
            asm volatile("s_waitcnt vmcnt(0)" ::: "memory");

            const float* phA = &sH[wv][c & 1][0][ng * 32];
            const float* phB = &sH[wv][c & 1][1][ng * 32];
            const float* pW  = W + c * 32 * RR + r0;
#pragma unroll
            for (int dq = 0; dq < 8; ++dq) {
                const int rot = ((dq - ng) & 7) << 2;   // XOR-rotated quad offset
                float4 w0 = *(const float4*)(pW + (dq * 4 + 0) * RR);
                float4 w1 = *(const float4*)(pW + (dq * 4 + 1) * RR);
                float4 w2 = *(const float4*)(pW + (dq * 4 + 2) * RR);
                float4 w3 = *(const float4*)(pW + (dq * 4 + 3) * RR);
                float4 hA0 = *(const float4*)(phA + 0 * 256 + rot);
                float4 hA1 = *(const float4*)(phA + 1 * 256 + rot);
                float4 hA2 = *(const float4*)(phA + 2 * 256 + rot);
                float4 hA3 = *(const float4*)(phA + 3 * 256 + rot);
                float4 hB0 = *(const float4*)(phB + 0 * 256 + rot);
                float4 hB1 = *(const float4*)(phB + 1 * 256 + rot);
                float4 hB2 = *(const float4*)(phB + 2 * 256 + rot);
                float4 hB3 = *(const float4*)(phB + 3 * 256 + rot);
                fma4(aA0, hA0.x, w0); fma4(aA0, hA0.y, w1); fma4(aA0, hA0.z, w2); fma4(aA0, hA0.w, w3);
                fma4(aA1, hA1.x, w0); fma4(aA1, hA1.y, w1); fma4(aA1, hA1.z, w2); fma4(aA1, hA1.w, w3);
                fma4(aA2, hA2.x, w0); fma4(aA2, hA2.y, w1); fma4(aA2, hA2.z, w2); fma4(aA2, hA2.w, w3);
                fma4(aA3, hA3.x, w0); fma4(aA3, hA3.y, w1); fma4(aA3, hA3.z, w2); fma4(aA3, hA3.w, w3);
                fma4(aB0, hB0.x, w0); fma4(aB0, hB0.y, w1); fma4(aB0, hB0.z, w2); fma4(aB0, hB0.w, w3);
                fma4(aB1, hB1.x, w0); fma4(aB1, hB1.y, w1); fma4(aB1, hB1.z, w2); fma4(aB1, hB1.w, w3);
                fma4(aB2, hB2.x, w0); fma4(aB2, hB2.y, w1); fma4(aB2, hB2.z, w2); fma4(aB2, hB2.w, w3);
                fma4(aB3, hB3.x, w0); fma4(aB3, hB3.y, w1); fma4(aB3, hB3.z, w2); fma4(aB3, hB3.w, w3);
            }

            asm volatile("s_waitcnt lgkmcnt(0)" ::: "memory");  // slot reads done
            if (c < 2) {
                issue_chunk(hg0, hg1, c + 2, c & 1);            // refill consumed slot
            } else if (pi == 0) {
                issue_chunk(hn0, hn1, c - 2, c & 1);            // pre-stage next pair
            }
        }

        // epilogue: per graph, pooled[r] = prod over 32 n, then score = pooled @ M^T + bl
#pragma unroll
        for (int gh = 0; gh < 2; ++gh) {
            float4 p;
            if (gh == 0) {
                p.x = aA0.x * aA1.x * aA2.x * aA3.x;
                p.y = aA0.y * aA1.y * aA2.y * aA3.y;
                p.z = aA0.z * aA1.z * aA2.z * aA3.z;
                p.w = aA0.w * aA1.w * aA2.w * aA3.w;
            } else {
                p.x = aB0.x * aB1.x * aB2.x * aB3.x;
                p.y = aB0.y * aB1.y * aB2.y * aB3.y;
                p.z = aB0.z * aB1.z * aB2.z * aB3.z;
                p.w = aB0.w * aB1.w * aB2.w * aB3.w;
            }
#pragma unroll
            for (int m = 8; m <= 32; m <<= 1) {   // butterfly over ng lanes
                p.x *= __shfl_xor(p.x, m);
                p.y *= __shfl_xor(p.y, m);
                p.z *= __shfl_xor(p.z, m);
                p.w *= __shfl_xor(p.w, m);
            }
            const float4* Mv = (const float4*)(M + lane * RR);
            float s = blv;
#pragma unroll
            for (int rq = 0; rq < 8; ++rq) {      // pooled quad rq lives in lane rq
                float4 pq;
                pq.x = __shfl(p.x, rq);
                pq.y = __shfl(p.y, rq);
                pq.z = __shfl(p.z, rq);
                pq.w = __shfl(p.w, rq);
                float4 m4 = Mv[rq];
                s = fmaf(pq.x, m4.x, s);
                s = fmaf(pq.y, m4.y, s);
                s = fmaf(pq.z, m4.z, s);
                s = fmaf(pq.w, m4.w, s);
            }
            out[(size_t)(gbase + pi * 2 + gh) * OO + lane] = s;
        }
    }
}

extern "C" void kernel_launch(void* const* d_in, const int* in_sizes, int n_in,
                              void* d_out, int out_size, void* d_ws, size_t ws_size,
                              hipStream_t stream) {
    const float* h  = (const float*)d_in[0];   // [16384,32,128]
    const float* W  = (const float*)d_in[1];   // [128,32]
    const float* V  = (const float*)d_in[2];   // [256,32]
    const float* Wl = (const float*)d_in[3];   // [64,256]
    const float* bl = (const float*)d_in[4];   // [64]
    float* out = (float*)d_out;                // [16384,64]
    float* M   = (float*)d_ws;                 // [64,32] scratch

    precompute_M_kernel<<<8, 256, 0, stream>>>(Wl, V, M);
    gin_main_kernel<<<2048, 128, 0, stream>>>(h, W, M, bl, out);
}

// Round 6
// 395.016 us; speedup vs baseline: 5.6387x; 5.6387x over previous
//
#include <hip/hip_runtime.h>
#include <math.h>

#define NG  16384
#define NN  32
#define DD  128
#define RR  32
#define OO  64
#define HHH 256

// MT[r][o] = sum_h Wl[o][h] * V[h][r]  — TRANSPOSED so the main kernel's
// per-lane readout column load is coalesced (lane o reads MT[r*64+o]).
__global__ void precompute_MT_kernel(const float* __restrict__ Wl,
                                     const float* __restrict__ V,
                                     float* __restrict__ MT) {
    int t = blockIdx.x * blockDim.x + threadIdx.x;   // 0..2047
    int o = t >> 5;
    int r = t & 31;
    float s = 0.f;
#pragma unroll 8
    for (int hh = 0; hh < HHH; ++hh)
        s = fmaf(Wl[o * HHH + hh], V[hh * RR + r], s);
    MT[r * OO + o] = s;
}

__device__ __forceinline__ void fma4(float4& a, float s, const float4& w) {
    a.x = fmaf(s, w.x, a.x);
    a.y = fmaf(s, w.y, a.y);
    a.z = fmaf(s, w.z, a.z);
    a.w = fmaf(s, w.w, a.w);
}

typedef const float __attribute__((address_space(1))) gfloat;
typedef float       __attribute__((address_space(3))) lfloat;

// R6 = R3 skeleton (W in LDS — global-W was R5's spill trigger) with:
//  - 2 graphs interleaved per wave: each W ds_read serves both graphs
//    (LDS reads 256 -> 192 per graph). dq body split A-then-B to cap
//    live float4 temps at 8.
//  - per-wave double-buffered DMA slots (2 slots x 2 graphs x 4 KB),
//    vmcnt(8) partial waits, full drain only at chunk 3.
//  - epilogue: butterfly (12 DS) + 1 LDS write + 8 broadcast reads (vs 32
//    bpermute), score against a per-lane MT column preloaded via 32
//    coalesced scalar loads at wave start.
// LDS/block = 16 (W) + 32 (h) + 1 (pooled) = 49 KB -> 3 blocks/CU, 12 waves.
__global__ __launch_bounds__(256, 2)
void gin_main_kernel(const float* __restrict__ hsrc,
                     const float* __restrict__ W,
                     const float* __restrict__ MT,
                     const float* __restrict__ bl,
                     float* __restrict__ out) {
    __shared__ float sW[DD * RR];          // [d][r], 16 KB, block-shared
    __shared__ float sH[4][2][2][1024];    // [wave][slot][graph][32n x 32d XOR]
    __shared__ float sP[4][2][32];         // [wave][graph] pooled exchange

    const int tid  = threadIdx.x;
    const int lane = tid & 63;
    const int wv   = tid >> 6;
    const int rg   = lane & 7;     // r-group: r = rg*4 .. rg*4+3
    const int ng   = lane >> 3;    // n-group: n = ng, ng+8, ng+16, ng+24
    const int r0   = rg * 4;
    const int rowL = lane >> 3;    // DMA: row within 8-row group
    const int t8   = lane & 7;     // DMA: slot within row
    const int sq   = (t8 + rowL) & 7;   // global quad stored in this slot

    {   // stage W once (straight copy — same [d][r] flat layout)
        const float4* Wv  = (const float4*)W;
        float4*       sWv = (float4*)sW;
#pragma unroll
        for (int k = 0; k < 4; ++k) sWv[tid + k * 256] = Wv[tid + k * 256];
    }

    // per-lane readout column + bias (VMEM, issued before any DMA)
    float mt[32];
#pragma unroll
    for (int r = 0; r < 32; ++r) mt[r] = MT[r * OO + lane];
    const float blv = bl[lane];
    __syncthreads();   // only block-wide barrier (sW ready)

    const int gbase = (blockIdx.x * 4 + wv) * 4;   // 4 graphs per wave

    // stage one 32x32f chunk of both graphs of a pair into slot `slot`
    auto issue_chunk = [&](const float* hgA, const float* hgB, int c, int slot) {
        const int goff = c * 32 + sq * 4;
#pragma unroll
        for (int j = 0; j < 4; ++j) {
            const float* gp = hgA + (j * 8 + rowL) * DD + goff;
            __builtin_amdgcn_global_load_lds((gfloat*)gp,
                                             (lfloat*)(&sH[wv][slot][0][j * 256]), 16, 0, 0);
        }
#pragma unroll
        for (int j = 0; j < 4; ++j) {
            const float* gp = hgB + (j * 8 + rowL) * DD + goff;
            __builtin_amdgcn_global_load_lds((gfloat*)gp,
                                             (lfloat*)(&sH[wv][slot][1][j * 256]), 16, 0, 0);
        }
    };

#pragma unroll 1
    for (int pi = 0; pi < 2; ++pi) {
        const float* hgA = hsrc + (size_t)(gbase + pi * 2) * (NN * DD);
        const float* hgB = hgA + NN * DD;

        float4 aA0 = make_float4(0.f, 0.f, 0.f, 0.f);
        float4 aA1 = aA0, aA2 = aA0, aA3 = aA0;              // graph A
        float4 aB0 = aA0, aB1 = aA0, aB2 = aA0, aB3 = aA0;   // graph B

        issue_chunk(hgA, hgB, 0, 0);
        issue_chunk(hgA, hgB, 1, 1);

#pragma unroll 1
        for (int c = 0; c < 4; ++c) {
            // c<3: chunk c done, next chunk's 8 DMAs may stay in flight.
            if (c < 3) asm volatile("s_waitcnt vmcnt(8)" ::: "memory");
            else       asm volatile("s_waitcnt vmcnt(0)" ::: "memory");

            const float* phA = &sH[wv][c & 1][0][ng * 32];
            const float* phB = &sH[wv][c & 1][1][ng * 32];
            const float* pW  = sW + c * 32 * RR + r0;
#pragma unroll
            for (int dq = 0; dq < 8; ++dq) {
                const int rot = ((dq - ng) & 7) << 2;   // XOR-rotated quad offset
                float4 w0 = *(const float4*)(pW + (dq * 4 + 0) * RR);
                float4 w1 = *(const float4*)(pW + (dq * 4 + 1) * RR);
                float4 w2 = *(const float4*)(pW + (dq * 4 + 2) * RR);
                float4 w3 = *(const float4*)(pW + (dq * 4 + 3) * RR);
                {   // graph A
                    float4 h0 = *(const float4*)(phA + 0 * 256 + rot);
                    float4 h1 = *(const float4*)(phA + 1 * 256 + rot);
                    float4 h2 = *(const float4*)(phA + 2 * 256 + rot);
                    float4 h3 = *(const float4*)(phA + 3 * 256 + rot);
                    fma4(aA0, h0.x, w0); fma4(aA0, h0.y, w1); fma4(aA0, h0.z, w2); fma4(aA0, h0.w, w3);
                    fma4(aA1, h1.x, w0); fma4(aA1, h1.y, w1); fma4(aA1, h1.z, w2); fma4(aA1, h1.w, w3);
                    fma4(aA2, h2.x, w0); fma4(aA2, h2.y, w1); fma4(aA2, h2.z, w2); fma4(aA2, h2.w, w3);
                    fma4(aA3, h3.x, w0); fma4(aA3, h3.y, w1); fma4(aA3, h3.z, w2); fma4(aA3, h3.w, w3);
                }
                {   // graph B (reuses the same W quads in registers)
                    float4 h0 = *(const float4*)(phB + 0 * 256 + rot);
                    float4 h1 = *(const float4*)(phB + 1 * 256 + rot);
                    float4 h2 = *(const float4*)(phB + 2 * 256 + rot);
                    float4 h3 = *(const float4*)(phB + 3 * 256 + rot);
                    fma4(aB0, h0.x, w0); fma4(aB0, h0.y, w1); fma4(aB0, h0.z, w2); fma4(aB0, h0.w, w3);
                    fma4(aB1, h1.x, w0); fma4(aB1, h1.y, w1); fma4(aB1, h1.z, w2); fma4(aB1, h1.w, w3);
                    fma4(aB2, h2.x, w0); fma4(aB2, h2.y, w1); fma4(aB2, h2.z, w2); fma4(aB2, h2.w, w3);
                    fma4(aB3, h3.x, w0); fma4(aB3, h3.y, w1); fma4(aB3, h3.z, w2); fma4(aB3, h3.w, w3);
                }
            }
            if (c < 2) {   // refill the slot just consumed (reads are drained:
                           // FMA deps forced lgkm completion; add explicit for safety)
                asm volatile("s_waitcnt lgkmcnt(0)" ::: "memory");
                issue_chunk(hgA, hgB, c + 2, c & 1);
            }
        }

        // epilogue: per graph, pooled[r] = prod over 32 n, then score = pooled@MT + bl
#pragma unroll
        for (int gh = 0; gh < 2; ++gh) {
            float4 p;
            if (gh == 0) {
                p.x = aA0.x * aA1.x * aA2.x * aA3.x;
                p.y = aA0.y * aA1.y * aA2.y * aA3.y;
                p.z = aA0.z * aA1.z * aA2.z * aA3.z;
                p.w = aA0.w * aA1.w * aA2.w * aA3.w;
            } else {
                p.x = aB0.x * aB1.x * aB2.x * aB3.x;
                p.y = aB0.y * aB1.y * aB2.y * aB3.y;
                p.z = aB0.z * aB1.z * aB2.z * aB3.z;
                p.w = aB0.w * aB1.w * aB2.w * aB3.w;
            }
#pragma unroll
            for (int m = 8; m <= 32; m <<= 1) {   // product across ng lanes
                p.x *= __shfl_xor(p.x, m);
                p.y *= __shfl_xor(p.y, m);
                p.z *= __shfl_xor(p.z, m);
                p.w *= __shfl_xor(p.w, m);
            }
            // exchange pooled via LDS: 8 lanes write their quad, all read 32 floats
            if (ng == 0) *(float4*)(&sP[wv][gh][r0]) = p;
            float s = blv;
#pragma unroll
            for (int rq = 0; rq < 8; ++rq) {
                float4 pq = *(const float4*)(&sP[wv][gh][rq * 4]);  // broadcast
                s = fmaf(pq.x, mt[rq * 4 + 0], s);
                s = fmaf(pq.y, mt[rq * 4 + 1], s);
                s = fmaf(pq.z, mt[rq * 4 + 2], s);
                s = fmaf(pq.w, mt[rq * 4 + 3], s);
            }
            out[(size_t)(gbase + pi * 2 + gh) * OO + lane] = s;
        }
    }
}

extern "C" void kernel_launch(void* const* d_in, const int* in_sizes, int n_in,
                              void* d_out, int out_size, void* d_ws, size_t ws_size,
                              hipStream_t stream) {
    const float* h  = (const float*)d_in[0];   // [16384,32,128]
    const float* W  = (const float*)d_in[1];   // [128,32]
    const float* V  = (const float*)d_in[2];   // [256,32]
    const float* Wl = (const float*)d_in[3];   // [64,256]
    const float* bl = (const float*)d_in[4];   // [64]
    float* out = (float*)d_out;                // [16384,64]
    float* MT  = (float*)d_ws;                 // [32,64] scratch (transposed M)

    precompute_MT_kernel<<<8, 256, 0, stream>>>(Wl, V, MT);
    gin_main_kernel<<<1024, 256, 0, stream>>>(h, W, MT, bl, out);
}